// Round 6
// baseline (3677.081 us; speedup 1.0000x reference)
//
#include <hip/hip_runtime.h>
#include <hip/hip_bf16.h>
#include <math.h>

#define B 32
#define S 512
#define W 8
#define CE 100       // CHAR_EMB
#define SE 100       // SUB_EMB
#define HD 200       // hidden per direction
#define G4 800       // 4*HD
#define IN2 200      // 2*CHAR_EMB
#define SUBV 100000
#define UNK 1
#define NL 4
#define SK (S - 2)   // 510
#define FEAT 500     // 2*HD + SE

__device__ __forceinline__ float fsig(float x) {
    return 1.f / (1.f + __expf(-x));
}
__device__ __forceinline__ float ftanh(float x) {
    float e = __expf(-2.f * fabsf(x));   // e in (0,1], overflow-safe
    float r = (1.f - e) / (1.f + e);
    return copysignf(r, x);
}

// ---------------- K0: transpose [800][200] -> [200][800] ----------------
__global__ void transpose_k(const float* __restrict__ in, float* __restrict__ out) {
    int o = blockIdx.x * 256 + threadIdx.x;   // 160000 elements
    if (o >= IN2 * G4) return;
    int k = o / G4, g = o % G4;
    out[o] = in[g * 200 + k];
}

// ---------------- K1: embedding concat -> x[B][S][200] ----------------
__global__ void embed_k(const int* __restrict__ chars, const int* __restrict__ bichars,
                        const float* __restrict__ cw, const float* __restrict__ bw,
                        float* __restrict__ x) {
    int t = blockIdx.x * 256 + threadIdx.x;
    if (t >= B * S * IN2) return;
    int c = t % IN2;
    int row = t / IN2;
    float v;
    if (c < CE) v = cw[(size_t)chars[row] * CE + c];
    else        v = bw[(size_t)bichars[row] * CE + (c - CE)];
    x[t] = v;
}

// ---------------- K2: xg = x @ WihT + b (both directions) ----------------
__global__ void xg_k(const float* __restrict__ x,
                     const float* __restrict__ WihT_f, const float* __restrict__ bf,
                     const float* __restrict__ WihT_b, const float* __restrict__ bb,
                     float* __restrict__ xgf, float* __restrict__ xgb) {
    const int dir = blockIdx.y;
    const float* WT   = dir ? WihT_b : WihT_f;
    const float* bias = dir ? bb : bf;
    float* out        = dir ? xgb : xgf;
    int r0 = blockIdx.x * 16;
    __shared__ float xs[16][IN2];
    for (int i = threadIdx.x; i < 16 * IN2; i += 256) {
        xs[i / IN2][i % IN2] = x[(size_t)(r0 + i / IN2) * IN2 + i % IN2];
    }
    __syncthreads();
    float acc[4][16];
    for (int q = 0; q < 4; q++)
        for (int r = 0; r < 16; r++) acc[q][r] = 0.f;
    int tid = threadIdx.x;
    for (int k = 0; k < IN2; k++) {
        const float* wrow = WT + (size_t)k * G4;
        float w0 = wrow[tid];
        float w1 = wrow[tid + 256];
        float w2 = wrow[tid + 512];
        float w3 = (tid < 32) ? wrow[tid + 768] : 0.f;
        for (int r = 0; r < 16; r++) {
            float xv = xs[r][k];
            acc[0][r] += w0 * xv;
            acc[1][r] += w1 * xv;
            acc[2][r] += w2 * xv;
            acc[3][r] += w3 * xv;
        }
    }
    for (int q = 0; q < 4; q++) {
        int g = tid + q * 256;
        if (g < G4) {
            float bv = bias[g];
            for (int r = 0; r < 16; r++)
                out[(size_t)(r0 + r) * G4 + g] = acc[q][r] + bv;
        }
    }
}

// ---------------- K3: LSTM recurrence, LDS-resident weights --------------
// grid = 128 blocks = 2 dirs x 16 batch-pairs x 4 slices; block = 1024 thr.
// Block owns a 50-hidden slice of TWO same-direction chains (b, b+16) that
// share the same Whh slice. The slice (200 gate-rows x 200 k = 160000 B) is
// staged ONCE into LDS in thread-order interleaved float4 layout:
//   w4[j][atid] at float-offset (j*800+atid)*4, j=0..11  (k = 50p+4j..+3)
//   wt2[atid]   at float-offset 38400 + atid*2           (k = 50p+48,49)
// Wave reads are contiguous 1024B -> bank-conflict-free. hsA/hsB/gbuf follow.
// Total LDS = 162400 B of the 163840 B/CU.
__global__ __launch_bounds__(1024)
void lstm_k(const float* __restrict__ xgf, const float* __restrict__ xgb,
            const float* __restrict__ Whh_f, const float* __restrict__ Whh_b,
            float* __restrict__ hf, float* __restrict__ hb, int* __restrict__ ctr) {
    __shared__ float lds[40600];
    int blk = blockIdx.x;
    int pairid = blk >> 2, slice = blk & 3;
    int dir = pairid >> 4;
    int bA = pairid & 15;
    int bB = bA + 16;
    const float* xg  = dir ? xgb : xgf;
    const float* Whh = dir ? Whh_b : Whh_f;
    float* hout      = dir ? hb : hf;
    int t = threadIdx.x;
    int c = t >> 2;          // gate column within slice (active c<200 <=> t<800)
    int p = t & 3;           // k-quarter
    bool active = (c < 200);
    int q = c / 50, jj = c % 50;
    int g_glob = q * 200 + slice * 50 + jj;   // row in Whh [800][200]

    float4* w4  = (float4*)lds;              // 12*800 float4 = 38400 floats
    float2* wt2 = (float2*)(lds + 38400);    // 800 float2   = 1600 floats
    float* hsA  = lds + 40000;
    float* hsB  = lds + 40200;
    float* gbuf = lds + 40400;

    // ---- stage weight slice into LDS (one time) ----
    if (active) {
        const float* wsrc = Whh + (size_t)g_glob * HD + 50 * p;
        #pragma unroll
        for (int j = 0; j < 12; j++) {
            float4 v;
            v.x = wsrc[4 * j + 0];
            v.y = wsrc[4 * j + 1];
            v.z = wsrc[4 * j + 2];
            v.w = wsrc[4 * j + 3];
            w4[j * 800 + t] = v;
        }
        float2 tv;
        tv.x = wsrc[48];
        tv.y = wsrc[49];
        wt2[t] = tv;
    }
    if (t < HD) { hsA[t] = 0.f; hsB[t] = 0.f; }
    float cstA = 0.f, cstB = 0.f;          // c-state, owned by t<50
    int* ctrA = ctr + (dir * 32 + bA) * 16;
    int* ctrB = ctr + (dir * 32 + bB) * 16;
    __syncthreads();

#define PHASE(hsX, cstX, bX, ctrX)                                             \
    {                                                                          \
        if (s > 0) {                                                           \
            if (t == 0) {                                                      \
                while (__hip_atomic_load(ctrX, __ATOMIC_RELAXED,               \
                                         __HIP_MEMORY_SCOPE_AGENT) < 4 * s) {} \
                __builtin_amdgcn_fence(__ATOMIC_ACQUIRE, "agent");             \
            }                                                                  \
            __syncthreads();                                                   \
            int tsp = dir ? (S - s) : (s - 1);                                 \
            if (t < HD) {                                                      \
                if (t / 50 != slice)                                           \
                    hsX[t] = __hip_atomic_load(                                \
                        &hout[((size_t)bX * S + tsp) * HD + t],                \
                        __ATOMIC_RELAXED, __HIP_MEMORY_SCOPE_AGENT);           \
            }                                                                  \
            __syncthreads();                                                   \
        }                                                                      \
        int ts = dir ? (S - 1 - s) : s;                                        \
        float acc = 0.f;                                                       \
        if (active) {                                                          \
            const float2* hp = (const float2*)(hsX + 50 * p);                  \
            float acc0 = 0.f, acc1 = 0.f;                                      \
            _Pragma("unroll")                                                  \
            for (int j = 0; j < 12; j++) {                                     \
                float4 wv = w4[j * 800 + t];                                   \
                float2 h0 = hp[2 * j];                                         \
                float2 h1 = hp[2 * j + 1];                                     \
                acc0 = fmaf(wv.y, h0.y, fmaf(wv.x, h0.x, acc0));               \
                acc1 = fmaf(wv.w, h1.y, fmaf(wv.z, h1.x, acc1));               \
            }                                                                  \
            float2 wt = wt2[t];                                                \
            float2 ht = hp[24];                                                \
            acc0 = fmaf(wt.y, ht.y, fmaf(wt.x, ht.x, acc0));                   \
            acc = acc0 + acc1;                                                 \
            acc += __shfl_xor(acc, 1);                                         \
            acc += __shfl_xor(acc, 2);                                         \
            if (p == 0)                                                        \
                gbuf[c] = acc + xg[((size_t)bX * S + ts) * G4 + g_glob];       \
        }                                                                      \
        __syncthreads();                                                       \
        if (t < 50) {                                                          \
            float ig = fsig(gbuf[t]);                                          \
            float fg = fsig(gbuf[50 + t]);                                     \
            float gg = ftanh(gbuf[100 + t]);                                   \
            float og = fsig(gbuf[150 + t]);                                    \
            cstX = fg * cstX + ig * gg;                                        \
            float h = og * ftanh(cstX);                                        \
            hsX[slice * 50 + t] = h;                                           \
            __hip_atomic_store(&hout[((size_t)bX * S + ts) * HD + slice * 50 + t], \
                               h, __ATOMIC_RELAXED, __HIP_MEMORY_SCOPE_AGENT); \
        }                                                                      \
        __syncthreads();                                                       \
        if (t == 0)                                                            \
            __hip_atomic_fetch_add(ctrX, 1, __ATOMIC_RELEASE,                  \
                                   __HIP_MEMORY_SCOPE_AGENT);                  \
    }

    for (int s = 0; s < S; s++) {
        PHASE(hsA, cstA, bA, ctrA)
        PHASE(hsB, cstB, bB, ctrB)
    }
#undef PHASE
}

// ---------------- K4: span features + subword emb + FFN ----------------
__global__ void out_k(const int* __restrict__ subwords,
                      const float* __restrict__ pre_w, const float* __restrict__ sub_w,
                      const float* __restrict__ hf, const float* __restrict__ hb,
                      const float* __restrict__ ffn_w, const float* __restrict__ ffn_b,
                      float* __restrict__ out) {
    int wave = (blockIdx.x * 256 + threadIdx.x) >> 6;
    int lane = threadIdx.x & 63;
    if (wave >= B * SK * W) return;
    int i = wave % W;
    int bk = wave / W;
    int k = bk % SK;
    int b = bk / SK;
    int end = k + i;
    float vscale = (end <= S - 3) ? 1.f : 0.f;
    int e1 = min(end + 1, S - 1);
    int e2 = min(end + 2, S - 1);
    const float* hfb = hf + (size_t)b * S * HD;
    const float* hbb = hb + (size_t)b * S * HD;
    int sw = subwords[wave];
    int sw2 = (sw >= SUBV) ? UNK : sw;
    float acc0 = 0, acc1 = 0, acc2 = 0, acc3 = 0;
    for (int j = lane; j < FEAT; j += 64) {
        float fv;
        if (j < HD) {
            fv = (hfb[(size_t)e1 * HD + j] - hfb[(size_t)k * HD + j]) * vscale;
        } else if (j < 2 * HD) {
            int jj = j - HD;
            fv = (hbb[(size_t)(k + 1) * HD + jj] - hbb[(size_t)e2 * HD + jj]) * vscale;
        } else {
            int jj = j - 2 * HD;
            fv = pre_w[(size_t)sw * SE + jj] + sub_w[(size_t)sw2 * SE + jj];
        }
        acc0 += ffn_w[j] * fv;
        acc1 += ffn_w[FEAT + j] * fv;
        acc2 += ffn_w[2 * FEAT + j] * fv;
        acc3 += ffn_w[3 * FEAT + j] * fv;
    }
    for (int off = 32; off; off >>= 1) {
        acc0 += __shfl_down(acc0, off);
        acc1 += __shfl_down(acc1, off);
        acc2 += __shfl_down(acc2, off);
        acc3 += __shfl_down(acc3, off);
    }
    if (lane == 0) {
        float* o = out + (size_t)wave * NL;
        o[0] = acc0 + ffn_b[0];
        o[1] = acc1 + ffn_b[1];
        o[2] = acc2 + ffn_b[2];
        o[3] = acc3 + ffn_b[3];
    }
}

extern "C" void kernel_launch(void* const* d_in, const int* in_sizes, int n_in,
                              void* d_out, int out_size, void* d_ws, size_t ws_size,
                              hipStream_t stream) {
    const int*   chars    = (const int*)d_in[0];
    const int*   bichars  = (const int*)d_in[1];
    const int*   subwords = (const int*)d_in[2];
    const float* cw    = (const float*)d_in[3];
    const float* bw    = (const float*)d_in[4];
    const float* subw  = (const float*)d_in[5];
    const float* prew  = (const float*)d_in[6];
    const float* Wih_f = (const float*)d_in[7];
    const float* Whh_f = (const float*)d_in[8];
    const float* b_f   = (const float*)d_in[9];
    const float* Wih_b = (const float*)d_in[10];
    const float* Whh_b = (const float*)d_in[11];
    const float* b_b   = (const float*)d_in[12];
    const float* ffn_w = (const float*)d_in[13];
    const float* ffn_b = (const float*)d_in[14];
    float* out = (float*)d_out;

    float* ws = (float*)d_ws;
    float* WihT_f = ws;                      // 160000 floats each
    float* WihT_b = WihT_f + 160000;
    float* x   = WihT_b + 160000;            // 3,276,800
    float* xgf = x + 3276800;                // 13,107,200
    float* xgb = xgf + 13107200;             // 13,107,200
    float* hf  = xgb + 13107200;             // 3,276,800
    float* hb  = hf + 3276800;               // 3,276,800
    int*   ctr = (int*)(hb + 3276800);       // 64 chains x 16 ints (64B padded)

    (void)hipMemsetAsync(ctr, 0, 64 * 16 * sizeof(int), stream);
    transpose_k<<<625, 256, 0, stream>>>(Wih_f, WihT_f);
    transpose_k<<<625, 256, 0, stream>>>(Wih_b, WihT_b);
    embed_k<<<(B * S * IN2 + 255) / 256, 256, 0, stream>>>(chars, bichars, cw, bw, x);
    xg_k<<<dim3(B * S / 16, 2), 256, 0, stream>>>(x, WihT_f, b_f, WihT_b, b_b, xgf, xgb);
    lstm_k<<<128, 1024, 0, stream>>>(xgf, xgb, Whh_f, Whh_b, hf, hb, ctr);
    out_k<<<(B * SK * W) / 4, 256, 0, stream>>>(subwords, prew, subw, hf, hb, ffn_w, ffn_b, out);
}

// Round 7
// 2321.770 us; speedup vs baseline: 1.5837x; 1.5837x over previous
//
#include <hip/hip_runtime.h>
#include <hip/hip_bf16.h>
#include <math.h>

#define B 32
#define S 512
#define W 8
#define CE 100       // CHAR_EMB
#define SE 100       // SUB_EMB
#define HD 200       // hidden per direction
#define G4 800       // 4*HD
#define IN2 200      // 2*CHAR_EMB
#define SUBV 100000
#define UNK 1
#define NL 4
#define SK (S - 2)   // 510
#define FEAT 500     // 2*HD + SE

__device__ __forceinline__ float fsig(float x) {
    return 1.f / (1.f + __expf(-x));
}
__device__ __forceinline__ float ftanh(float x) {
    float e = __expf(-2.f * fabsf(x));   // e in (0,1], overflow-safe
    float r = (1.f - e) / (1.f + e);
    return copysignf(r, x);
}

// ---------------- K0: transpose [800][200] -> [200][800] ----------------
__global__ void transpose_k(const float* __restrict__ in, float* __restrict__ out) {
    int o = blockIdx.x * 256 + threadIdx.x;   // 160000 elements
    if (o >= IN2 * G4) return;
    int k = o / G4, g = o % G4;
    out[o] = in[g * 200 + k];
}

// ---------------- K1: embedding concat -> x[B][S][200] ----------------
__global__ void embed_k(const int* __restrict__ chars, const int* __restrict__ bichars,
                        const float* __restrict__ cw, const float* __restrict__ bw,
                        float* __restrict__ x) {
    int t = blockIdx.x * 256 + threadIdx.x;
    if (t >= B * S * IN2) return;
    int c = t % IN2;
    int row = t / IN2;
    float v;
    if (c < CE) v = cw[(size_t)chars[row] * CE + c];
    else        v = bw[(size_t)bichars[row] * CE + (c - CE)];
    x[t] = v;
}

// ---------------- K2: xg = x @ WihT + b (both directions) ----------------
__global__ void xg_k(const float* __restrict__ x,
                     const float* __restrict__ WihT_f, const float* __restrict__ bf,
                     const float* __restrict__ WihT_b, const float* __restrict__ bb,
                     float* __restrict__ xgf, float* __restrict__ xgb) {
    const int dir = blockIdx.y;
    const float* WT   = dir ? WihT_b : WihT_f;
    const float* bias = dir ? bb : bf;
    float* out        = dir ? xgb : xgf;
    int r0 = blockIdx.x * 16;
    __shared__ float xs[16][IN2];
    for (int i = threadIdx.x; i < 16 * IN2; i += 256) {
        xs[i / IN2][i % IN2] = x[(size_t)(r0 + i / IN2) * IN2 + i % IN2];
    }
    __syncthreads();
    float acc[4][16];
    for (int q = 0; q < 4; q++)
        for (int r = 0; r < 16; r++) acc[q][r] = 0.f;
    int tid = threadIdx.x;
    for (int k = 0; k < IN2; k++) {
        const float* wrow = WT + (size_t)k * G4;
        float w0 = wrow[tid];
        float w1 = wrow[tid + 256];
        float w2 = wrow[tid + 512];
        float w3 = (tid < 32) ? wrow[tid + 768] : 0.f;
        for (int r = 0; r < 16; r++) {
            float xv = xs[r][k];
            acc[0][r] += w0 * xv;
            acc[1][r] += w1 * xv;
            acc[2][r] += w2 * xv;
            acc[3][r] += w3 * xv;
        }
    }
    for (int q = 0; q < 4; q++) {
        int g = tid + q * 256;
        if (g < G4) {
            float bv = bias[g];
            for (int r = 0; r < 16; r++)
                out[(size_t)(r0 + r) * G4 + g] = acc[q][r] + bv;
        }
    }
}

// ---------------- K3: LSTM recurrence, data-flag sync + xg prefetch ------
// grid = 128 blocks = 2 dirs x 16 batch-pairs x 4 slices; block = 1024 thr.
// Block owns a 50-hidden slice of TWO same-direction chains (b, b+16) that
// share the same Whh slice (LDS-resident, 160000 B, conflict-free layout).
// Cross-block h exchange: hf/hb are pre-filled with NaN; writers do relaxed
// agent-scope stores, readers poll the word itself until !isnan -> a single
// L3 round trip, no counters, no fences. xg values are prefetched one phase
// ahead into registers so their latency hides under the poll window.
__global__ __launch_bounds__(1024)
void lstm_k(const float* __restrict__ xgf, const float* __restrict__ xgb,
            const float* __restrict__ Whh_f, const float* __restrict__ Whh_b,
            float* __restrict__ hf, float* __restrict__ hb) {
    __shared__ float lds[40600];
    int blk = blockIdx.x;
    int pairid = blk >> 2, slice = blk & 3;
    int dir = pairid >> 4;
    int bA = pairid & 15;
    int bB = bA + 16;
    const float* xg  = dir ? xgb : xgf;
    const float* Whh = dir ? Whh_b : Whh_f;
    float* hout      = dir ? hb : hf;
    int t = threadIdx.x;
    int c = t >> 2;          // gate column within slice (active c<200 <=> t<800)
    int p = t & 3;           // k-quarter
    bool active = (c < 200);
    int q = c / 50, jj = c % 50;
    int g_glob = q * 200 + slice * 50 + jj;   // row in Whh [800][200]

    float4* w4  = (float4*)lds;              // 12*800 float4 = 38400 floats
    float2* wt2 = (float2*)(lds + 38400);    // 800 float2   = 1600 floats
    float* hsA  = lds + 40000;
    float* hsB  = lds + 40200;
    float* gbuf = lds + 40400;

    // ---- stage weight slice into LDS (one time) ----
    if (active) {
        const float* wsrc = Whh + (size_t)g_glob * HD + 50 * p;
        #pragma unroll
        for (int j = 0; j < 12; j++) {
            float4 v;
            v.x = wsrc[4 * j + 0];
            v.y = wsrc[4 * j + 1];
            v.z = wsrc[4 * j + 2];
            v.w = wsrc[4 * j + 3];
            w4[j * 800 + t] = v;
        }
        float2 tv;
        tv.x = wsrc[48];
        tv.y = wsrc[49];
        wt2[t] = tv;
    }
    if (t < HD) { hsA[t] = 0.f; hsB[t] = 0.f; }
    float cstA = 0.f, cstB = 0.f;          // c-state, owned by t<50
    // prefetch xg for s=0
    float xgA = 0.f, xgB = 0.f;
    {
        int ts0 = dir ? (S - 1) : 0;
        if (active && p == 0) {
            xgA = xg[((size_t)bA * S + ts0) * G4 + g_glob];
            xgB = xg[((size_t)bB * S + ts0) * G4 + g_glob];
        }
    }
    __syncthreads();

#define PHASE(hsX, cstX, bX, xgX)                                              \
    {                                                                          \
        float xgn = 0.f;                                                       \
        if (active && p == 0)                                                  \
            xgn = xg[((size_t)bX * S + tsn) * G4 + g_glob];   /* prefetch */   \
        if (s > 0 && t < HD && (t / 50) != slice) {                            \
            const float* src = &hout[((size_t)bX * S + tsp) * HD + t];         \
            float v;                                                           \
            do {                                                               \
                v = __hip_atomic_load(src, __ATOMIC_RELAXED,                   \
                                      __HIP_MEMORY_SCOPE_AGENT);               \
            } while (v != v);            /* NaN sentinel -> wait for data */   \
            hsX[t] = v;                                                        \
        }                                                                      \
        __syncthreads();                                                       \
        if (active) {                                                          \
            const float2* hp = (const float2*)(hsX + 50 * p);                  \
            float acc0 = 0.f, acc1 = 0.f;                                      \
            _Pragma("unroll")                                                  \
            for (int j = 0; j < 12; j++) {                                     \
                float4 wv = w4[j * 800 + t];                                   \
                float2 h0 = hp[2 * j];                                         \
                float2 h1 = hp[2 * j + 1];                                     \
                acc0 = fmaf(wv.y, h0.y, fmaf(wv.x, h0.x, acc0));               \
                acc1 = fmaf(wv.w, h1.y, fmaf(wv.z, h1.x, acc1));               \
            }                                                                  \
            float2 wt = wt2[t];                                                \
            float2 ht = hp[24];                                                \
            acc0 = fmaf(wt.y, ht.y, fmaf(wt.x, ht.x, acc0));                   \
            float acc = acc0 + acc1;                                           \
            acc += __shfl_xor(acc, 1);                                         \
            acc += __shfl_xor(acc, 2);                                         \
            if (p == 0) gbuf[c] = acc + xgX;                                   \
        }                                                                      \
        __syncthreads();                                                       \
        if (t < 50) {                                                          \
            float ig = fsig(gbuf[t]);                                          \
            float fg = fsig(gbuf[50 + t]);                                     \
            float gg = ftanh(gbuf[100 + t]);                                   \
            float og = fsig(gbuf[150 + t]);                                    \
            cstX = fg * cstX + ig * gg;                                        \
            float h = og * ftanh(cstX);                                        \
            hsX[slice * 50 + t] = h;                                           \
            __hip_atomic_store(&hout[((size_t)bX * S + ts) * HD + slice * 50 + t], \
                               h, __ATOMIC_RELAXED, __HIP_MEMORY_SCOPE_AGENT); \
        }                                                                      \
        __syncthreads();                                                       \
        xgX = xgn;                                                             \
    }

    for (int s = 0; s < S; s++) {
        int ts  = dir ? (S - 1 - s) : s;
        int tsp = dir ? (S - s) : (s - 1);               // step s-1's time index
        int tsn = (s + 1 < S) ? (dir ? S - 2 - s : s + 1) : ts;  // next step
        PHASE(hsA, cstA, bA, xgA)
        PHASE(hsB, cstB, bB, xgB)
    }
#undef PHASE
}

// ---------------- K4: span features + subword emb + FFN ----------------
__global__ void out_k(const int* __restrict__ subwords,
                      const float* __restrict__ pre_w, const float* __restrict__ sub_w,
                      const float* __restrict__ hf, const float* __restrict__ hb,
                      const float* __restrict__ ffn_w, const float* __restrict__ ffn_b,
                      float* __restrict__ out) {
    int wave = (blockIdx.x * 256 + threadIdx.x) >> 6;
    int lane = threadIdx.x & 63;
    if (wave >= B * SK * W) return;
    int i = wave % W;
    int bk = wave / W;
    int k = bk % SK;
    int b = bk / SK;
    int end = k + i;
    float vscale = (end <= S - 3) ? 1.f : 0.f;
    int e1 = min(end + 1, S - 1);
    int e2 = min(end + 2, S - 1);
    const float* hfb = hf + (size_t)b * S * HD;
    const float* hbb = hb + (size_t)b * S * HD;
    int sw = subwords[wave];
    int sw2 = (sw >= SUBV) ? UNK : sw;
    float acc0 = 0, acc1 = 0, acc2 = 0, acc3 = 0;
    for (int j = lane; j < FEAT; j += 64) {
        float fv;
        if (j < HD) {
            fv = (hfb[(size_t)e1 * HD + j] - hfb[(size_t)k * HD + j]) * vscale;
        } else if (j < 2 * HD) {
            int jj = j - HD;
            fv = (hbb[(size_t)(k + 1) * HD + jj] - hbb[(size_t)e2 * HD + jj]) * vscale;
        } else {
            int jj = j - 2 * HD;
            fv = pre_w[(size_t)sw * SE + jj] + sub_w[(size_t)sw2 * SE + jj];
        }
        acc0 += ffn_w[j] * fv;
        acc1 += ffn_w[FEAT + j] * fv;
        acc2 += ffn_w[2 * FEAT + j] * fv;
        acc3 += ffn_w[3 * FEAT + j] * fv;
    }
    for (int off = 32; off; off >>= 1) {
        acc0 += __shfl_down(acc0, off);
        acc1 += __shfl_down(acc1, off);
        acc2 += __shfl_down(acc2, off);
        acc3 += __shfl_down(acc3, off);
    }
    if (lane == 0) {
        float* o = out + (size_t)wave * NL;
        o[0] = acc0 + ffn_b[0];
        o[1] = acc1 + ffn_b[1];
        o[2] = acc2 + ffn_b[2];
        o[3] = acc3 + ffn_b[3];
    }
}

extern "C" void kernel_launch(void* const* d_in, const int* in_sizes, int n_in,
                              void* d_out, int out_size, void* d_ws, size_t ws_size,
                              hipStream_t stream) {
    const int*   chars    = (const int*)d_in[0];
    const int*   bichars  = (const int*)d_in[1];
    const int*   subwords = (const int*)d_in[2];
    const float* cw    = (const float*)d_in[3];
    const float* bw    = (const float*)d_in[4];
    const float* subw  = (const float*)d_in[5];
    const float* prew  = (const float*)d_in[6];
    const float* Wih_f = (const float*)d_in[7];
    const float* Whh_f = (const float*)d_in[8];
    const float* b_f   = (const float*)d_in[9];
    const float* Wih_b = (const float*)d_in[10];
    const float* Whh_b = (const float*)d_in[11];
    const float* b_b   = (const float*)d_in[12];
    const float* ffn_w = (const float*)d_in[13];
    const float* ffn_b = (const float*)d_in[14];
    float* out = (float*)d_out;

    float* ws = (float*)d_ws;
    float* WihT_f = ws;                      // 160000 floats each
    float* WihT_b = WihT_f + 160000;
    float* x   = WihT_b + 160000;            // 3,276,800
    float* xgf = x + 3276800;                // 13,107,200
    float* xgb = xgf + 13107200;             // 13,107,200
    float* hf  = xgb + 13107200;             // 3,276,800
    float* hb  = hf + 3276800;               // 3,276,800

    // NaN-fill h buffers: the data word itself is the readiness flag.
    (void)hipMemsetAsync(hf, 0xFF, 3276800 * sizeof(float), stream);
    (void)hipMemsetAsync(hb, 0xFF, 3276800 * sizeof(float), stream);
    transpose_k<<<625, 256, 0, stream>>>(Wih_f, WihT_f);
    transpose_k<<<625, 256, 0, stream>>>(Wih_b, WihT_b);
    embed_k<<<(B * S * IN2 + 255) / 256, 256, 0, stream>>>(chars, bichars, cw, bw, x);
    xg_k<<<dim3(B * S / 16, 2), 256, 0, stream>>>(x, WihT_f, b_f, WihT_b, b_b, xgf, xgb);
    lstm_k<<<128, 1024, 0, stream>>>(xgf, xgb, Whh_f, Whh_b, hf, hb);
    out_k<<<(B * SK * W) / 4, 256, 0, stream>>>(subwords, prew, subw, hf, hb, ffn_w, ffn_b, out);
}

// Round 8
// 2273.343 us; speedup vs baseline: 1.6175x; 1.0213x over previous
//
#include <hip/hip_runtime.h>
#include <hip/hip_bf16.h>
#include <math.h>

#define B 32
#define S 512
#define W 8
#define CE 100       // CHAR_EMB
#define SE 100       // SUB_EMB
#define HD 200       // hidden per direction
#define G4 800       // 4*HD
#define IN2 200      // 2*CHAR_EMB
#define SUBV 100000
#define UNK 1
#define NL 4
#define SK (S - 2)   // 510
#define FEAT 500     // 2*HD + SE

__device__ __forceinline__ float fsig(float x) {
    return 1.f / (1.f + __expf(-x));
}
__device__ __forceinline__ float ftanh(float x) {
    float e = __expf(-2.f * fabsf(x));   // e in (0,1], overflow-safe
    float r = (1.f - e) / (1.f + e);
    return copysignf(r, x);
}

// ---------------- K0: transpose [800][200] -> [200][800] ----------------
__global__ void transpose_k(const float* __restrict__ in, float* __restrict__ out) {
    int o = blockIdx.x * 256 + threadIdx.x;   // 160000 elements
    if (o >= IN2 * G4) return;
    int k = o / G4, g = o % G4;
    out[o] = in[g * 200 + k];
}

// ---------------- K1: embedding concat -> x[B][S][200] ----------------
__global__ void embed_k(const int* __restrict__ chars, const int* __restrict__ bichars,
                        const float* __restrict__ cw, const float* __restrict__ bw,
                        float* __restrict__ x) {
    int t = blockIdx.x * 256 + threadIdx.x;
    if (t >= B * S * IN2) return;
    int c = t % IN2;
    int row = t / IN2;
    float v;
    if (c < CE) v = cw[(size_t)chars[row] * CE + c];
    else        v = bw[(size_t)bichars[row] * CE + (c - CE)];
    x[t] = v;
}

// ---------------- K2: xg = x @ WihT + b (both directions) ----------------
__global__ void xg_k(const float* __restrict__ x,
                     const float* __restrict__ WihT_f, const float* __restrict__ bf,
                     const float* __restrict__ WihT_b, const float* __restrict__ bb,
                     float* __restrict__ xgf, float* __restrict__ xgb) {
    const int dir = blockIdx.y;
    const float* WT   = dir ? WihT_b : WihT_f;
    const float* bias = dir ? bb : bf;
    float* out        = dir ? xgb : xgf;
    int r0 = blockIdx.x * 16;
    __shared__ float xs[16][IN2];
    for (int i = threadIdx.x; i < 16 * IN2; i += 256) {
        xs[i / IN2][i % IN2] = x[(size_t)(r0 + i / IN2) * IN2 + i % IN2];
    }
    __syncthreads();
    float acc[4][16];
    for (int q = 0; q < 4; q++)
        for (int r = 0; r < 16; r++) acc[q][r] = 0.f;
    int tid = threadIdx.x;
    for (int k = 0; k < IN2; k++) {
        const float* wrow = WT + (size_t)k * G4;
        float w0 = wrow[tid];
        float w1 = wrow[tid + 256];
        float w2 = wrow[tid + 512];
        float w3 = (tid < 32) ? wrow[tid + 768] : 0.f;
        for (int r = 0; r < 16; r++) {
            float xv = xs[r][k];
            acc[0][r] += w0 * xv;
            acc[1][r] += w1 * xv;
            acc[2][r] += w2 * xv;
            acc[3][r] += w3 * xv;
        }
    }
    for (int q = 0; q < 4; q++) {
        int g = tid + q * 256;
        if (g < G4) {
            float bv = bias[g];
            for (int r = 0; r < 16; r++)
                out[(size_t)(r0 + r) * G4 + g] = acc[q][r] + bv;
        }
    }
}

// ---------------- K3: LSTM recurrence, XCD-colocated slice blocks --------
// grid = 128 blocks; blk = slice*32 + (dir*16 + bA). Under round-robin
// XCD = blockIdx % 8, all 4 slice-blocks of a pair-chain land on the SAME
// XCD (32 % 8 == 0), so the h-exchange store->poll path stays in that
// XCD's L2 (heuristic: placement affects speed only, never correctness).
// Block owns a 50-hidden slice of TWO same-direction chains (b, b+16) that
// share the same Whh slice (LDS-resident, 160000 B, conflict-free layout).
// Cross-block h exchange: hf/hb pre-filled with NaN; writers do relaxed
// agent-scope stores, readers poll the word itself until !isnan. xg values
// prefetched one phase ahead.
__global__ __launch_bounds__(1024)
void lstm_k(const float* __restrict__ xgf, const float* __restrict__ xgb,
            const float* __restrict__ Whh_f, const float* __restrict__ Whh_b,
            float* __restrict__ hf, float* __restrict__ hb) {
    __shared__ float lds[40600];
    int blk = blockIdx.x;
    int slice = blk >> 5;                // 0..3
    int pg = blk & 31;                   // dir*16 + bA  -> XCD = pg % 8
    int dir = pg >> 4;
    int bA = pg & 15;
    int bB = bA + 16;
    const float* xg  = dir ? xgb : xgf;
    const float* Whh = dir ? Whh_b : Whh_f;
    float* hout      = dir ? hb : hf;
    int t = threadIdx.x;
    int c = t >> 2;          // gate column within slice (active c<200 <=> t<800)
    int p = t & 3;           // k-quarter
    bool active = (c < 200);
    int q = c / 50, jj = c % 50;
    int g_glob = q * 200 + slice * 50 + jj;   // row in Whh [800][200]

    float4* w4  = (float4*)lds;              // 12*800 float4 = 38400 floats
    float2* wt2 = (float2*)(lds + 38400);    // 800 float2   = 1600 floats
    float* hsA  = lds + 40000;
    float* hsB  = lds + 40200;
    float* gbuf = lds + 40400;

    // ---- stage weight slice into LDS (one time) ----
    if (active) {
        const float* wsrc = Whh + (size_t)g_glob * HD + 50 * p;
        #pragma unroll
        for (int j = 0; j < 12; j++) {
            float4 v;
            v.x = wsrc[4 * j + 0];
            v.y = wsrc[4 * j + 1];
            v.z = wsrc[4 * j + 2];
            v.w = wsrc[4 * j + 3];
            w4[j * 800 + t] = v;
        }
        float2 tv;
        tv.x = wsrc[48];
        tv.y = wsrc[49];
        wt2[t] = tv;
    }
    if (t < HD) { hsA[t] = 0.f; hsB[t] = 0.f; }
    float cstA = 0.f, cstB = 0.f;          // c-state, owned by t<50
    // prefetch xg for s=0
    float xgA = 0.f, xgB = 0.f;
    {
        int ts0 = dir ? (S - 1) : 0;
        if (active && p == 0) {
            xgA = xg[((size_t)bA * S + ts0) * G4 + g_glob];
            xgB = xg[((size_t)bB * S + ts0) * G4 + g_glob];
        }
    }
    __syncthreads();

#define PHASE(hsX, cstX, bX, xgX)                                              \
    {                                                                          \
        float xgn = 0.f;                                                       \
        if (active && p == 0)                                                  \
            xgn = xg[((size_t)bX * S + tsn) * G4 + g_glob];   /* prefetch */   \
        if (s > 0 && t < HD && (t / 50) != slice) {                            \
            const float* src = &hout[((size_t)bX * S + tsp) * HD + t];         \
            float v;                                                           \
            do {                                                               \
                v = __hip_atomic_load(src, __ATOMIC_RELAXED,                   \
                                      __HIP_MEMORY_SCOPE_AGENT);               \
            } while (v != v);            /* NaN sentinel -> wait for data */   \
            hsX[t] = v;                                                        \
        }                                                                      \
        __syncthreads();                                                       \
        if (active) {                                                          \
            const float2* hp = (const float2*)(hsX + 50 * p);                  \
            float acc0 = 0.f, acc1 = 0.f;                                      \
            _Pragma("unroll")                                                  \
            for (int j = 0; j < 12; j++) {                                     \
                float4 wv = w4[j * 800 + t];                                   \
                float2 h0 = hp[2 * j];                                         \
                float2 h1 = hp[2 * j + 1];                                     \
                acc0 = fmaf(wv.y, h0.y, fmaf(wv.x, h0.x, acc0));               \
                acc1 = fmaf(wv.w, h1.y, fmaf(wv.z, h1.x, acc1));               \
            }                                                                  \
            float2 wt = wt2[t];                                                \
            float2 ht = hp[24];                                                \
            acc0 = fmaf(wt.y, ht.y, fmaf(wt.x, ht.x, acc0));                   \
            float acc = acc0 + acc1;                                           \
            acc += __shfl_xor(acc, 1);                                         \
            acc += __shfl_xor(acc, 2);                                         \
            if (p == 0) gbuf[c] = acc + xgX;                                   \
        }                                                                      \
        __syncthreads();                                                       \
        if (t < 50) {                                                          \
            float ig = fsig(gbuf[t]);                                          \
            float fg = fsig(gbuf[50 + t]);                                     \
            float gg = ftanh(gbuf[100 + t]);                                   \
            float og = fsig(gbuf[150 + t]);                                    \
            cstX = fg * cstX + ig * gg;                                        \
            float h = og * ftanh(cstX);                                        \
            hsX[slice * 50 + t] = h;                                           \
            __hip_atomic_store(&hout[((size_t)bX * S + ts) * HD + slice * 50 + t], \
                               h, __ATOMIC_RELAXED, __HIP_MEMORY_SCOPE_AGENT); \
        }                                                                      \
        __syncthreads();                                                       \
        xgX = xgn;                                                             \
    }

    for (int s = 0; s < S; s++) {
        int ts  = dir ? (S - 1 - s) : s;
        int tsp = dir ? (S - s) : (s - 1);               // step s-1's time index
        int tsn = (s + 1 < S) ? (dir ? S - 2 - s : s + 1) : ts;  // next step
        PHASE(hsA, cstA, bA, xgA)
        PHASE(hsB, cstB, bB, xgB)
    }
#undef PHASE
}

// ---------------- K4: span features + subword emb + FFN ----------------
__global__ void out_k(const int* __restrict__ subwords,
                      const float* __restrict__ pre_w, const float* __restrict__ sub_w,
                      const float* __restrict__ hf, const float* __restrict__ hb,
                      const float* __restrict__ ffn_w, const float* __restrict__ ffn_b,
                      float* __restrict__ out) {
    int wave = (blockIdx.x * 256 + threadIdx.x) >> 6;
    int lane = threadIdx.x & 63;
    if (wave >= B * SK * W) return;
    int i = wave % W;
    int bk = wave / W;
    int k = bk % SK;
    int b = bk / SK;
    int end = k + i;
    float vscale = (end <= S - 3) ? 1.f : 0.f;
    int e1 = min(end + 1, S - 1);
    int e2 = min(end + 2, S - 1);
    const float* hfb = hf + (size_t)b * S * HD;
    const float* hbb = hb + (size_t)b * S * HD;
    int sw = subwords[wave];
    int sw2 = (sw >= SUBV) ? UNK : sw;
    float acc0 = 0, acc1 = 0, acc2 = 0, acc3 = 0;
    for (int j = lane; j < FEAT; j += 64) {
        float fv;
        if (j < HD) {
            fv = (hfb[(size_t)e1 * HD + j] - hfb[(size_t)k * HD + j]) * vscale;
        } else if (j < 2 * HD) {
            int jj = j - HD;
            fv = (hbb[(size_t)(k + 1) * HD + jj] - hbb[(size_t)e2 * HD + jj]) * vscale;
        } else {
            int jj = j - 2 * HD;
            fv = pre_w[(size_t)sw * SE + jj] + sub_w[(size_t)sw2 * SE + jj];
        }
        acc0 += ffn_w[j] * fv;
        acc1 += ffn_w[FEAT + j] * fv;
        acc2 += ffn_w[2 * FEAT + j] * fv;
        acc3 += ffn_w[3 * FEAT + j] * fv;
    }
    for (int off = 32; off; off >>= 1) {
        acc0 += __shfl_down(acc0, off);
        acc1 += __shfl_down(acc1, off);
        acc2 += __shfl_down(acc2, off);
        acc3 += __shfl_down(acc3, off);
    }
    if (lane == 0) {
        float* o = out + (size_t)wave * NL;
        o[0] = acc0 + ffn_b[0];
        o[1] = acc1 + ffn_b[1];
        o[2] = acc2 + ffn_b[2];
        o[3] = acc3 + ffn_b[3];
    }
}

extern "C" void kernel_launch(void* const* d_in, const int* in_sizes, int n_in,
                              void* d_out, int out_size, void* d_ws, size_t ws_size,
                              hipStream_t stream) {
    const int*   chars    = (const int*)d_in[0];
    const int*   bichars  = (const int*)d_in[1];
    const int*   subwords = (const int*)d_in[2];
    const float* cw    = (const float*)d_in[3];
    const float* bw    = (const float*)d_in[4];
    const float* subw  = (const float*)d_in[5];
    const float* prew  = (const float*)d_in[6];
    const float* Wih_f = (const float*)d_in[7];
    const float* Whh_f = (const float*)d_in[8];
    const float* b_f   = (const float*)d_in[9];
    const float* Wih_b = (const float*)d_in[10];
    const float* Whh_b = (const float*)d_in[11];
    const float* b_b   = (const float*)d_in[12];
    const float* ffn_w = (const float*)d_in[13];
    const float* ffn_b = (const float*)d_in[14];
    float* out = (float*)d_out;

    float* ws = (float*)d_ws;
    float* WihT_f = ws;                      // 160000 floats each
    float* WihT_b = WihT_f + 160000;
    float* x   = WihT_b + 160000;            // 3,276,800
    float* xgf = x + 3276800;                // 13,107,200
    float* xgb = xgf + 13107200;             // 13,107,200
    float* hf  = xgb + 13107200;             // 3,276,800
    float* hb  = hf + 3276800;               // 3,276,800

    // NaN-fill h buffers: the data word itself is the readiness flag.
    (void)hipMemsetAsync(hf, 0xFF, 3276800 * sizeof(float), stream);
    (void)hipMemsetAsync(hb, 0xFF, 3276800 * sizeof(float), stream);
    transpose_k<<<625, 256, 0, stream>>>(Wih_f, WihT_f);
    transpose_k<<<625, 256, 0, stream>>>(Wih_b, WihT_b);
    embed_k<<<(B * S * IN2 + 255) / 256, 256, 0, stream>>>(chars, bichars, cw, bw, x);
    xg_k<<<dim3(B * S / 16, 2), 256, 0, stream>>>(x, WihT_f, b_f, WihT_b, b_b, xgf, xgb);
    lstm_k<<<128, 1024, 0, stream>>>(xgf, xgb, Whh_f, Whh_b, hf, hb);
    out_k<<<(B * SK * W) / 4, 256, 0, stream>>>(subwords, prew, subw, hf, hb, ffn_w, ffn_b, out);
}

// Round 9
// 2173.264 us; speedup vs baseline: 1.6920x; 1.0460x over previous
//
#include <hip/hip_runtime.h>
#include <hip/hip_bf16.h>
#include <math.h>

#define B 32
#define S 512
#define W 8
#define CE 100       // CHAR_EMB
#define SE 100       // SUB_EMB
#define HD 200       // hidden per direction
#define G4 800       // 4*HD
#define IN2 200      // 2*CHAR_EMB
#define SUBV 100000
#define UNK 1
#define NL 4
#define SK (S - 2)   // 510
#define FEAT 500     // 2*HD + SE

__device__ __forceinline__ float fsig(float x) {
    return 1.f / (1.f + __expf(-x));
}
__device__ __forceinline__ float ftanh(float x) {
    float e = __expf(-2.f * fabsf(x));   // e in (0,1], overflow-safe
    float r = (1.f - e) / (1.f + e);
    return copysignf(r, x);
}

// 64-lane sum; result valid in lane 63. DPP adds run on the VALU pipe,
// keeping the LDS unit free (the current bottleneck).
__device__ __forceinline__ float wave_sum64(float v) {
#if __has_builtin(__builtin_amdgcn_update_dpp)
#define DPPADD(C) { int x_ = __builtin_amdgcn_update_dpp(0, __float_as_int(v), C, 0xf, 0xf, true); \
                    v += __int_as_float(x_); }
    DPPADD(0x111)  // row_shr:1
    DPPADD(0x112)  // row_shr:2
    DPPADD(0x114)  // row_shr:4
    DPPADD(0x118)  // row_shr:8  -> lane15/31/47/63 hold row sums
    DPPADD(0x142)  // row_bcast15 -> lane31 = rows0+1, lane63 = rows2+3
    DPPADD(0x143)  // row_bcast31 -> lane63 = total
#undef DPPADD
    return v;
#else
    v += __shfl_xor(v, 1);  v += __shfl_xor(v, 2);  v += __shfl_xor(v, 4);
    v += __shfl_xor(v, 8);  v += __shfl_xor(v, 16); v += __shfl_xor(v, 32);
    return v;
#endif
}

__device__ __forceinline__ float dot4(float4 w, float4 h) {
    return fmaf(w.w, h.w, fmaf(w.z, h.z, fmaf(w.y, h.y, w.x * h.x)));
}

// ---------------- K0: transpose [800][200] -> [200][800] ----------------
__global__ void transpose_k(const float* __restrict__ in, float* __restrict__ out) {
    int o = blockIdx.x * 256 + threadIdx.x;   // 160000 elements
    if (o >= IN2 * G4) return;
    int k = o / G4, g = o % G4;
    out[o] = in[g * 200 + k];
}

// ---------------- K1: embedding concat -> x[B][S][200] ----------------
__global__ void embed_k(const int* __restrict__ chars, const int* __restrict__ bichars,
                        const float* __restrict__ cw, const float* __restrict__ bw,
                        float* __restrict__ x) {
    int t = blockIdx.x * 256 + threadIdx.x;
    if (t >= B * S * IN2) return;
    int c = t % IN2;
    int row = t / IN2;
    float v;
    if (c < CE) v = cw[(size_t)chars[row] * CE + c];
    else        v = bw[(size_t)bichars[row] * CE + (c - CE)];
    x[t] = v;
}

// ---------------- K2: xg = x @ WihT + b (both directions) ----------------
__global__ void xg_k(const float* __restrict__ x,
                     const float* __restrict__ WihT_f, const float* __restrict__ bf,
                     const float* __restrict__ WihT_b, const float* __restrict__ bb,
                     float* __restrict__ xgf, float* __restrict__ xgb) {
    const int dir = blockIdx.y;
    const float* WT   = dir ? WihT_b : WihT_f;
    const float* bias = dir ? bb : bf;
    float* out        = dir ? xgb : xgf;
    int r0 = blockIdx.x * 16;
    __shared__ float xs[16][IN2];
    for (int i = threadIdx.x; i < 16 * IN2; i += 256) {
        xs[i / IN2][i % IN2] = x[(size_t)(r0 + i / IN2) * IN2 + i % IN2];
    }
    __syncthreads();
    float acc[4][16];
    for (int q = 0; q < 4; q++)
        for (int r = 0; r < 16; r++) acc[q][r] = 0.f;
    int tid = threadIdx.x;
    for (int k = 0; k < IN2; k++) {
        const float* wrow = WT + (size_t)k * G4;
        float w0 = wrow[tid];
        float w1 = wrow[tid + 256];
        float w2 = wrow[tid + 512];
        float w3 = (tid < 32) ? wrow[tid + 768] : 0.f;
        for (int r = 0; r < 16; r++) {
            float xv = xs[r][k];
            acc[0][r] += w0 * xv;
            acc[1][r] += w1 * xv;
            acc[2][r] += w2 * xv;
            acc[3][r] += w3 * xv;
        }
    }
    for (int q = 0; q < 4; q++) {
        int g = tid + q * 256;
        if (g < G4) {
            float bv = bias[g];
            for (int r = 0; r < 16; r++)
                out[(size_t)(r0 + r) * G4 + g] = acc[q][r] + bv;
        }
    }
}

// ---------------- K3: LSTM recurrence, lane-k matvec + DPP reduce --------
// grid = 256 blocks = 8 slices x (2 dirs x 16 pairs); blk = sl*32 + pg keeps
// all 8 slices of a pair-chain on one XCD (XCD = blk%8 = pg%8). T=256.
// Block owns 25 hidden units (100 gate columns) of chains bA,bB (shared Whh).
// Wave q = gate q, 25 columns. k is distributed over LANES: lane l holds
// h[4l..4l+3] (one b128 per wave per phase), weights are lane-distinct b128
// (full 800B utilization), reduce via 6 DPP adds on the VALU pipe.
// hs[200..255] stay zero so lanes 50..63 contribute exact zeros.
// A/B superphases: [fill(cur) || act(prev)] bar [compute(cur)] bar — the
// NaN-poll exchange latency hides under the other chain's compute.
__global__ __launch_bounds__(256)
void lstm_k(const float* __restrict__ xgf, const float* __restrict__ xgb,
            const float* __restrict__ Whh_f, const float* __restrict__ Whh_b,
            float* __restrict__ hf, float* __restrict__ hb) {
    __shared__ float4 wlds[5064];                 // [col*50+l]; pad for lane>=50 reads
    __shared__ __align__(16) float hsA[256];
    __shared__ __align__(16) float hsB[256];
    __shared__ __align__(16) float gbA[112];      // [gate*28 + unit]
    __shared__ __align__(16) float gbB[112];

    const int blk = blockIdx.x;
    const int sl  = blk >> 5;                     // slice 0..7 (25 units)
    const int pg  = blk & 31;                     // dir*16 + pair
    const int dir = pg >> 4;
    const int bA  = pg & 15;
    const int bB  = bA + 16;
    const float* xg  = dir ? xgb : xgf;
    const float* Whh = dir ? Whh_b : Whh_f;
    float* hout      = dir ? hb : hf;

    const int t = threadIdx.x;
    const int lane = t & 63;
    const int q = t >> 6;                         // wave id = gate id

    // stage weights: wlds[col*50+l] = Whh[row(col)][4l..4l+3], col = q*25+u
    for (int i = t; i < 5000; i += 256) {
        int col = i / 50, l = i - col * 50;
        int row = (col / 25) * 200 + sl * 25 + (col % 25);
        wlds[i] = *(const float4*)(Whh + (size_t)row * HD + 4 * l);
    }
    hsA[t] = 0.f;                                 // incl. zero tail 200..255
    hsB[t] = 0.f;

    const bool is_act = (t >= 224) && (t < 249);  // wave3 lanes 32..56
    const int u = t - 224;
    float cstA = 0.f, cstB = 0.f;
    float xA0=0,xA1=0,xA2=0,xA3=0, xB0=0,xB1=0,xB2=0,xB3=0;
    if (is_act) {
        int ts0 = dir ? (S - 1) : 0;
        const float* pa = xg + ((size_t)bA * S + ts0) * G4 + sl * 25 + u;
        const float* pb = xg + ((size_t)bB * S + ts0) * G4 + sl * 25 + u;
        xA0 = pa[0]; xA1 = pa[200]; xA2 = pa[400]; xA3 = pa[600];
        xB0 = pb[0]; xB1 = pb[200]; xB2 = pb[400]; xB3 = pb[600];
    }
    __syncthreads();

    for (int s = 0; s < S; s++) {
        const int ts  = dir ? (S - 1 - s) : s;          // time of step s
        const int tsp = dir ? (S - s)     : (s - 1);    // time of step s-1
        const int tsn = (s + 1 < S) ? (dir ? (S - 2 - s) : (s + 1)) : ts;

        // ---- SP1: fill A(s) || act B(s-1) ----
        if (s > 0) {
            if (t < 200 && (t / 25) != sl) {
                const float* src = &hout[((size_t)bA * S + tsp) * HD + t];
                float v;
                do { v = __hip_atomic_load(src, __ATOMIC_RELAXED,
                                           __HIP_MEMORY_SCOPE_AGENT); } while (v != v);
                hsA[t] = v;
            }
            if (is_act) {
                float ig = fsig(gbB[u] + xB0);
                float fg = fsig(gbB[28 + u] + xB1);
                float gt = ftanh(gbB[56 + u] + xB2);
                float og = fsig(gbB[84 + u] + xB3);
                cstB = fg * cstB + ig * gt;
                float h = og * ftanh(cstB);
                hsB[sl * 25 + u] = h;
                __hip_atomic_store(&hout[((size_t)bB * S + tsp) * HD + sl * 25 + u], h,
                                   __ATOMIC_RELAXED, __HIP_MEMORY_SCOPE_AGENT);
                const float* pn = xg + ((size_t)bB * S + ts) * G4 + sl * 25 + u;
                xB0 = pn[0]; xB1 = pn[200]; xB2 = pn[400]; xB3 = pn[600];
            }
        }
        __syncthreads();
        // ---- compute A(s) ----
        {
            float4 hv = ((const float4*)hsA)[lane];
            float* gq = gbA + q * 28;
            const int cb = q * 25;
            #pragma unroll
            for (int ug = 0; ug < 6; ug++) {
                float a0, a1, a2, a3;
                { float4 w = wlds[(cb + 4*ug + 0) * 50 + lane]; a0 = wave_sum64(dot4(w, hv)); }
                { float4 w = wlds[(cb + 4*ug + 1) * 50 + lane]; a1 = wave_sum64(dot4(w, hv)); }
                { float4 w = wlds[(cb + 4*ug + 2) * 50 + lane]; a2 = wave_sum64(dot4(w, hv)); }
                { float4 w = wlds[(cb + 4*ug + 3) * 50 + lane]; a3 = wave_sum64(dot4(w, hv)); }
                if (lane == 63) *(float4*)(gq + 4 * ug) = float4{a0, a1, a2, a3};
            }
            { float4 w = wlds[(cb + 24) * 50 + lane];
              float a = wave_sum64(dot4(w, hv));
              if (lane == 63) gq[24] = a; }
        }
        __syncthreads();
        // ---- SP2: fill B(s) || act A(s) ----
        if (s > 0 && t < 200 && (t / 25) != sl) {
            const float* src = &hout[((size_t)bB * S + tsp) * HD + t];
            float v;
            do { v = __hip_atomic_load(src, __ATOMIC_RELAXED,
                                       __HIP_MEMORY_SCOPE_AGENT); } while (v != v);
            hsB[t] = v;
        }
        if (is_act) {
            float ig = fsig(gbA[u] + xA0);
            float fg = fsig(gbA[28 + u] + xA1);
            float gt = ftanh(gbA[56 + u] + xA2);
            float og = fsig(gbA[84 + u] + xA3);
            cstA = fg * cstA + ig * gt;
            float h = og * ftanh(cstA);
            hsA[sl * 25 + u] = h;
            __hip_atomic_store(&hout[((size_t)bA * S + ts) * HD + sl * 25 + u], h,
                               __ATOMIC_RELAXED, __HIP_MEMORY_SCOPE_AGENT);
            const float* pn = xg + ((size_t)bA * S + tsn) * G4 + sl * 25 + u;
            xA0 = pn[0]; xA1 = pn[200]; xA2 = pn[400]; xA3 = pn[600];
        }
        __syncthreads();
        // ---- compute B(s) ----
        {
            float4 hv = ((const float4*)hsB)[lane];
            float* gq = gbB + q * 28;
            const int cb = q * 25;
            #pragma unroll
            for (int ug = 0; ug < 6; ug++) {
                float a0, a1, a2, a3;
                { float4 w = wlds[(cb + 4*ug + 0) * 50 + lane]; a0 = wave_sum64(dot4(w, hv)); }
                { float4 w = wlds[(cb + 4*ug + 1) * 50 + lane]; a1 = wave_sum64(dot4(w, hv)); }
                { float4 w = wlds[(cb + 4*ug + 2) * 50 + lane]; a2 = wave_sum64(dot4(w, hv)); }
                { float4 w = wlds[(cb + 4*ug + 3) * 50 + lane]; a3 = wave_sum64(dot4(w, hv)); }
                if (lane == 63) *(float4*)(gq + 4 * ug) = float4{a0, a1, a2, a3};
            }
            { float4 w = wlds[(cb + 24) * 50 + lane];
              float a = wave_sum64(dot4(w, hv));
              if (lane == 63) gq[24] = a; }
        }
        __syncthreads();
    }
    // epilogue: act B(S-1)
    if (is_act) {
        const int tl = dir ? 0 : (S - 1);
        float ig = fsig(gbB[u] + xB0);
        float fg = fsig(gbB[28 + u] + xB1);
        float gt = ftanh(gbB[56 + u] + xB2);
        float og = fsig(gbB[84 + u] + xB3);
        cstB = fg * cstB + ig * gt;
        float h = og * ftanh(cstB);
        __hip_atomic_store(&hout[((size_t)bB * S + tl) * HD + sl * 25 + u], h,
                           __ATOMIC_RELAXED, __HIP_MEMORY_SCOPE_AGENT);
    }
}

// ---------------- K4: span features + subword emb + FFN ----------------
__global__ void out_k(const int* __restrict__ subwords,
                      const float* __restrict__ pre_w, const float* __restrict__ sub_w,
                      const float* __restrict__ hf, const float* __restrict__ hb,
                      const float* __restrict__ ffn_w, const float* __restrict__ ffn_b,
                      float* __restrict__ out) {
    int wave = (blockIdx.x * 256 + threadIdx.x) >> 6;
    int lane = threadIdx.x & 63;
    if (wave >= B * SK * W) return;
    int i = wave % W;
    int bk = wave / W;
    int k = bk % SK;
    int b = bk / SK;
    int end = k + i;
    float vscale = (end <= S - 3) ? 1.f : 0.f;
    int e1 = min(end + 1, S - 1);
    int e2 = min(end + 2, S - 1);
    const float* hfb = hf + (size_t)b * S * HD;
    const float* hbb = hb + (size_t)b * S * HD;
    int sw = subwords[wave];
    int sw2 = (sw >= SUBV) ? UNK : sw;
    float acc0 = 0, acc1 = 0, acc2 = 0, acc3 = 0;
    for (int j = lane; j < FEAT; j += 64) {
        float fv;
        if (j < HD) {
            fv = (hfb[(size_t)e1 * HD + j] - hfb[(size_t)k * HD + j]) * vscale;
        } else if (j < 2 * HD) {
            int jj = j - HD;
            fv = (hbb[(size_t)(k + 1) * HD + jj] - hbb[(size_t)e2 * HD + jj]) * vscale;
        } else {
            int jj = j - 2 * HD;
            fv = pre_w[(size_t)sw * SE + jj] + sub_w[(size_t)sw2 * SE + jj];
        }
        acc0 += ffn_w[j] * fv;
        acc1 += ffn_w[FEAT + j] * fv;
        acc2 += ffn_w[2 * FEAT + j] * fv;
        acc3 += ffn_w[3 * FEAT + j] * fv;
    }
    for (int off = 32; off; off >>= 1) {
        acc0 += __shfl_down(acc0, off);
        acc1 += __shfl_down(acc1, off);
        acc2 += __shfl_down(acc2, off);
        acc3 += __shfl_down(acc3, off);
    }
    if (lane == 0) {
        float* o = out + (size_t)wave * NL;
        o[0] = acc0 + ffn_b[0];
        o[1] = acc1 + ffn_b[1];
        o[2] = acc2 + ffn_b[2];
        o[3] = acc3 + ffn_b[3];
    }
}

extern "C" void kernel_launch(void* const* d_in, const int* in_sizes, int n_in,
                              void* d_out, int out_size, void* d_ws, size_t ws_size,
                              hipStream_t stream) {
    const int*   chars    = (const int*)d_in[0];
    const int*   bichars  = (const int*)d_in[1];
    const int*   subwords = (const int*)d_in[2];
    const float* cw    = (const float*)d_in[3];
    const float* bw    = (const float*)d_in[4];
    const float* subw  = (const float*)d_in[5];
    const float* prew  = (const float*)d_in[6];
    const float* Wih_f = (const float*)d_in[7];
    const float* Whh_f = (const float*)d_in[8];
    const float* b_f   = (const float*)d_in[9];
    const float* Wih_b = (const float*)d_in[10];
    const float* Whh_b = (const float*)d_in[11];
    const float* b_b   = (const float*)d_in[12];
    const float* ffn_w = (const float*)d_in[13];
    const float* ffn_b = (const float*)d_in[14];
    float* out = (float*)d_out;

    float* ws = (float*)d_ws;
    float* WihT_f = ws;                      // 160000 floats each
    float* WihT_b = WihT_f + 160000;
    float* x   = WihT_b + 160000;            // 3,276,800
    float* xgf = x + 3276800;                // 13,107,200
    float* xgb = xgf + 13107200;             // 13,107,200
    float* hf  = xgb + 13107200;             // 3,276,800
    float* hb  = hf + 3276800;               // 3,276,800

    // NaN-fill h buffers: the data word itself is the readiness flag.
    (void)hipMemsetAsync(hf, 0xFF, 3276800 * sizeof(float), stream);
    (void)hipMemsetAsync(hb, 0xFF, 3276800 * sizeof(float), stream);
    transpose_k<<<625, 256, 0, stream>>>(Wih_f, WihT_f);
    transpose_k<<<625, 256, 0, stream>>>(Wih_b, WihT_b);
    embed_k<<<(B * S * IN2 + 255) / 256, 256, 0, stream>>>(chars, bichars, cw, bw, x);
    xg_k<<<dim3(B * S / 16, 2), 256, 0, stream>>>(x, WihT_f, b_f, WihT_b, b_b, xgf, xgb);
    lstm_k<<<256, 256, 0, stream>>>(xgf, xgb, Whh_f, Whh_b, hf, hb);
    out_k<<<(B * SK * W) / 4, 256, 0, stream>>>(subwords, prew, subw, hf, hb, ffn_w, ffn_b, out);
}

// Round 10
// 1499.020 us; speedup vs baseline: 2.4530x; 1.4498x over previous
//
#include <hip/hip_runtime.h>
#include <hip/hip_bf16.h>
#include <math.h>

#define B 32
#define S 512
#define W 8
#define CE 100       // CHAR_EMB
#define SE 100       // SUB_EMB
#define HD 200       // hidden per direction
#define G4 800       // 4*HD
#define IN2 200      // 2*CHAR_EMB
#define SUBV 100000
#define UNK 1
#define NL 4
#define SK (S - 2)   // 510
#define FEAT 500     // 2*HD + SE

__device__ __forceinline__ float fsig(float x) {
    return 1.f / (1.f + __expf(-x));
}
__device__ __forceinline__ float ftanh(float x) {
    float e = __expf(-2.f * fabsf(x));   // e in (0,1], overflow-safe
    float r = (1.f - e) / (1.f + e);
    return copysignf(r, x);
}

// 64-lane sum; result valid in lane 63. DPP adds run on the VALU pipe.
__device__ __forceinline__ float wave_sum64(float v) {
#if __has_builtin(__builtin_amdgcn_update_dpp)
#define DPPADD(C) { int x_ = __builtin_amdgcn_update_dpp(0, __float_as_int(v), C, 0xf, 0xf, true); \
                    v += __int_as_float(x_); }
    DPPADD(0x111)  // row_shr:1
    DPPADD(0x112)  // row_shr:2
    DPPADD(0x114)  // row_shr:4
    DPPADD(0x118)  // row_shr:8  -> lane15/31/47/63 hold row sums
    DPPADD(0x142)  // row_bcast15 -> lane31 = rows0+1, lane63 = rows2+3
    DPPADD(0x143)  // row_bcast31 -> lane63 = total
#undef DPPADD
    return v;
#else
    v += __shfl_xor(v, 1);  v += __shfl_xor(v, 2);  v += __shfl_xor(v, 4);
    v += __shfl_xor(v, 8);  v += __shfl_xor(v, 16); v += __shfl_xor(v, 32);
    return v;
#endif
}

__device__ __forceinline__ float dot4(float4 w, float4 h) {
    return fmaf(w.w, h.w, fmaf(w.z, h.z, fmaf(w.y, h.y, w.x * h.x)));
}

// ---------------- K0: transpose [800][200] -> [200][800] ----------------
__global__ void transpose_k(const float* __restrict__ in, float* __restrict__ out) {
    int o = blockIdx.x * 256 + threadIdx.x;   // 160000 elements
    if (o >= IN2 * G4) return;
    int k = o / G4, g = o % G4;
    out[o] = in[g * 200 + k];
}

// ---------------- K1: embedding concat -> x[B][S][200] ----------------
__global__ void embed_k(const int* __restrict__ chars, const int* __restrict__ bichars,
                        const float* __restrict__ cw, const float* __restrict__ bw,
                        float* __restrict__ x) {
    int t = blockIdx.x * 256 + threadIdx.x;
    if (t >= B * S * IN2) return;
    int c = t % IN2;
    int row = t / IN2;
    float v;
    if (c < CE) v = cw[(size_t)chars[row] * CE + c];
    else        v = bw[(size_t)bichars[row] * CE + (c - CE)];
    x[t] = v;
}

// ---------------- K2: xg = x @ WihT + b (both directions) ----------------
__global__ void xg_k(const float* __restrict__ x,
                     const float* __restrict__ WihT_f, const float* __restrict__ bf,
                     const float* __restrict__ WihT_b, const float* __restrict__ bb,
                     float* __restrict__ xgf, float* __restrict__ xgb) {
    const int dir = blockIdx.y;
    const float* WT   = dir ? WihT_b : WihT_f;
    const float* bias = dir ? bb : bf;
    float* out        = dir ? xgb : xgf;
    int r0 = blockIdx.x * 16;
    __shared__ float xs[16][IN2];
    for (int i = threadIdx.x; i < 16 * IN2; i += 256) {
        xs[i / IN2][i % IN2] = x[(size_t)(r0 + i / IN2) * IN2 + i % IN2];
    }
    __syncthreads();
    float acc[4][16];
    for (int q = 0; q < 4; q++)
        for (int r = 0; r < 16; r++) acc[q][r] = 0.f;
    int tid = threadIdx.x;
    for (int k = 0; k < IN2; k++) {
        const float* wrow = WT + (size_t)k * G4;
        float w0 = wrow[tid];
        float w1 = wrow[tid + 256];
        float w2 = wrow[tid + 512];
        float w3 = (tid < 32) ? wrow[tid + 768] : 0.f;
        for (int r = 0; r < 16; r++) {
            float xv = xs[r][k];
            acc[0][r] += w0 * xv;
            acc[1][r] += w1 * xv;
            acc[2][r] += w2 * xv;
            acc[3][r] += w3 * xv;
        }
    }
    for (int q = 0; q < 4; q++) {
        int g = tid + q * 256;
        if (g < G4) {
            float bv = bias[g];
            for (int r = 0; r < 16; r++)
                out[(size_t)(r0 + r) * G4 + g] = acc[q][r] + bv;
        }
    }
}

// ---------------- K3: LSTM recurrence, lane-k matvec, 16 waves -----------
// grid = 256 blocks = 8 slices x (2 dirs x 16 pairs); blk = sl*32 + pg keeps
// all 8 slices of a pair-chain on one XCD (XCD = blk%8 = pg%8). T=1024
// (16 waves, 4/SIMD) so dep-chain + LDS latency hides across waves.
// Block owns 25 hidden units (100 gate-cols, col c = gate*25+unit) of chains
// bA,bB (shared Whh). k over LANES: lane l holds h[4l..4l+3]; per col one
// lane-distinct ds_read_b128 of weights + dot4 + 6-DPP reduce (lane63 owns
// result). Wave w computes cols c = w + 16j. hs[200..255] zero so lanes
// 50..63 contribute exact zeros. A/B superphases: [fill(cur) || act(prev)]
// bar [compute(cur)] bar — NaN-poll exchange hides under sibling compute.
__global__ __launch_bounds__(1024)
void lstm_k(const float* __restrict__ xgf, const float* __restrict__ xgb,
            const float* __restrict__ Whh_f, const float* __restrict__ Whh_b,
            float* __restrict__ hf, float* __restrict__ hb) {
    __shared__ float4 wlds[5064];                 // [col*50+l]; pad for lane>=50
    __shared__ __align__(16) float hsA[256];
    __shared__ __align__(16) float hsB[256];
    __shared__ __align__(16) float gbA[112];      // [gate*25 + unit], padded
    __shared__ __align__(16) float gbB[112];

    const int blk = blockIdx.x;
    const int sl  = blk >> 5;                     // slice 0..7 (25 units)
    const int pg  = blk & 31;                     // dir*16 + pair
    const int dir = pg >> 4;
    const int bA  = pg & 15;
    const int bB  = bA + 16;
    const float* xg  = dir ? xgb : xgf;
    const float* Whh = dir ? Whh_b : Whh_f;
    float* hout      = dir ? hb : hf;

    const int t = threadIdx.x;
    const int lane = t & 63;
    const int w = t >> 6;                         // wave id 0..15

    // stage weights: wlds[col*50+l] = Whh[row(col)][4l..4l+3]
    // col = gate*25+unit -> row = gate*200 + sl*25 + unit
    for (int i = t; i < 5000; i += 1024) {
        int col = i / 50, l = i - col * 50;
        int row = (col / 25) * 200 + sl * 25 + (col % 25);
        wlds[i] = *(const float4*)(Whh + (size_t)row * HD + 4 * l);
    }
    if (t < 256) { hsA[t] = 0.f; hsB[t] = 0.f; }

    const bool is_act = (t >= 224) && (t < 249);  // 25 threads (wave 3)
    const int u = t - 224;
    float cstA = 0.f, cstB = 0.f;
    float xA0=0,xA1=0,xA2=0,xA3=0, xB0=0,xB1=0,xB2=0,xB3=0;
    if (is_act) {
        int ts0 = dir ? (S - 1) : 0;
        const float* pa = xg + ((size_t)bA * S + ts0) * G4 + sl * 25 + u;
        const float* pb = xg + ((size_t)bB * S + ts0) * G4 + sl * 25 + u;
        xA0 = pa[0]; xA1 = pa[200]; xA2 = pa[400]; xA3 = pa[600];
        xB0 = pb[0]; xB1 = pb[200]; xB2 = pb[400]; xB3 = pb[600];
    }
    __syncthreads();

#define COMPUTE(hsX, gbX)                                                      \
    {                                                                          \
        float4 hv = ((const float4*)hsX)[lane];                                \
        _Pragma("unroll")                                                      \
        for (int j = 0; j < 7; j++) {                                          \
            int c = w + 16 * j;                                                \
            if (c < 100) {                                                     \
                float4 wv = wlds[c * 50 + lane];                               \
                float a = wave_sum64(dot4(wv, hv));                            \
                if (lane == 63) gbX[c] = a;                                    \
            }                                                                  \
        }                                                                      \
    }

    for (int s = 0; s < S; s++) {
        const int ts  = dir ? (S - 1 - s) : s;          // time of step s
        const int tsp = dir ? (S - s)     : (s - 1);    // time of step s-1
        const int tsn = (s + 1 < S) ? (dir ? (S - 2 - s) : (s + 1)) : ts;

        // ---- SP1: fill A(s) || act B(s-1) ----
        if (s > 0) {
            if (t < 200 && (t / 25) != sl) {
                const float* src = &hout[((size_t)bA * S + tsp) * HD + t];
                float v;
                do { v = __hip_atomic_load(src, __ATOMIC_RELAXED,
                                           __HIP_MEMORY_SCOPE_AGENT); } while (v != v);
                hsA[t] = v;
            }
            if (is_act) {
                float ig = fsig(gbB[u] + xB0);
                float fg = fsig(gbB[25 + u] + xB1);
                float gt = ftanh(gbB[50 + u] + xB2);
                float og = fsig(gbB[75 + u] + xB3);
                cstB = fg * cstB + ig * gt;
                float h = og * ftanh(cstB);
                hsB[sl * 25 + u] = h;
                __hip_atomic_store(&hout[((size_t)bB * S + tsp) * HD + sl * 25 + u], h,
                                   __ATOMIC_RELAXED, __HIP_MEMORY_SCOPE_AGENT);
                const float* pn = xg + ((size_t)bB * S + ts) * G4 + sl * 25 + u;
                xB0 = pn[0]; xB1 = pn[200]; xB2 = pn[400]; xB3 = pn[600];
            }
        }
        __syncthreads();
        COMPUTE(hsA, gbA)
        __syncthreads();
        // ---- SP2: fill B(s) || act A(s) ----
        if (s > 0 && t < 200 && (t / 25) != sl) {
            const float* src = &hout[((size_t)bB * S + tsp) * HD + t];
            float v;
            do { v = __hip_atomic_load(src, __ATOMIC_RELAXED,
                                       __HIP_MEMORY_SCOPE_AGENT); } while (v != v);
            hsB[t] = v;
        }
        if (is_act) {
            float ig = fsig(gbA[u] + xA0);
            float fg = fsig(gbA[25 + u] + xA1);
            float gt = ftanh(gbA[50 + u] + xA2);
            float og = fsig(gbA[75 + u] + xA3);
            cstA = fg * cstA + ig * gt;
            float h = og * ftanh(cstA);
            hsA[sl * 25 + u] = h;
            __hip_atomic_store(&hout[((size_t)bA * S + ts) * HD + sl * 25 + u], h,
                               __ATOMIC_RELAXED, __HIP_MEMORY_SCOPE_AGENT);
            const float* pn = xg + ((size_t)bA * S + tsn) * G4 + sl * 25 + u;
            xA0 = pn[0]; xA1 = pn[200]; xA2 = pn[400]; xA3 = pn[600];
        }
        __syncthreads();
        COMPUTE(hsB, gbB)
        __syncthreads();
    }
    // epilogue: act B(S-1)
    if (is_act) {
        const int tl = dir ? 0 : (S - 1);
        float ig = fsig(gbB[u] + xB0);
        float fg = fsig(gbB[25 + u] + xB1);
        float gt = ftanh(gbB[50 + u] + xB2);
        float og = fsig(gbB[75 + u] + xB3);
        cstB = fg * cstB + ig * gt;
        float h = og * ftanh(cstB);
        __hip_atomic_store(&hout[((size_t)bB * S + tl) * HD + sl * 25 + u], h,
                           __ATOMIC_RELAXED, __HIP_MEMORY_SCOPE_AGENT);
    }
#undef COMPUTE
}

// ---------------- K4: span features + subword emb + FFN ----------------
__global__ void out_k(const int* __restrict__ subwords,
                      const float* __restrict__ pre_w, const float* __restrict__ sub_w,
                      const float* __restrict__ hf, const float* __restrict__ hb,
                      const float* __restrict__ ffn_w, const float* __restrict__ ffn_b,
                      float* __restrict__ out) {
    int wave = (blockIdx.x * 256 + threadIdx.x) >> 6;
    int lane = threadIdx.x & 63;
    if (wave >= B * SK * W) return;
    int i = wave % W;
    int bk = wave / W;
    int k = bk % SK;
    int b = bk / SK;
    int end = k + i;
    float vscale = (end <= S - 3) ? 1.f : 0.f;
    int e1 = min(end + 1, S - 1);
    int e2 = min(end + 2, S - 1);
    const float* hfb = hf + (size_t)b * S * HD;
    const float* hbb = hb + (size_t)b * S * HD;
    int sw = subwords[wave];
    int sw2 = (sw >= SUBV) ? UNK : sw;
    float acc0 = 0, acc1 = 0, acc2 = 0, acc3 = 0;
    for (int j = lane; j < FEAT; j += 64) {
        float fv;
        if (j < HD) {
            fv = (hfb[(size_t)e1 * HD + j] - hfb[(size_t)k * HD + j]) * vscale;
        } else if (j < 2 * HD) {
            int jj = j - HD;
            fv = (hbb[(size_t)(k + 1) * HD + jj] - hbb[(size_t)e2 * HD + jj]) * vscale;
        } else {
            int jj = j - 2 * HD;
            fv = pre_w[(size_t)sw * SE + jj] + sub_w[(size_t)sw2 * SE + jj];
        }
        acc0 += ffn_w[j] * fv;
        acc1 += ffn_w[FEAT + j] * fv;
        acc2 += ffn_w[2 * FEAT + j] * fv;
        acc3 += ffn_w[3 * FEAT + j] * fv;
    }
    for (int off = 32; off; off >>= 1) {
        acc0 += __shfl_down(acc0, off);
        acc1 += __shfl_down(acc1, off);
        acc2 += __shfl_down(acc2, off);
        acc3 += __shfl_down(acc3, off);
    }
    if (lane == 0) {
        float* o = out + (size_t)wave * NL;
        o[0] = acc0 + ffn_b[0];
        o[1] = acc1 + ffn_b[1];
        o[2] = acc2 + ffn_b[2];
        o[3] = acc3 + ffn_b[3];
    }
}

extern "C" void kernel_launch(void* const* d_in, const int* in_sizes, int n_in,
                              void* d_out, int out_size, void* d_ws, size_t ws_size,
                              hipStream_t stream) {
    const int*   chars    = (const int*)d_in[0];
    const int*   bichars  = (const int*)d_in[1];
    const int*   subwords = (const int*)d_in[2];
    const float* cw    = (const float*)d_in[3];
    const float* bw    = (const float*)d_in[4];
    const float* subw  = (const float*)d_in[5];
    const float* prew  = (const float*)d_in[6];
    const float* Wih_f = (const float*)d_in[7];
    const float* Whh_f = (const float*)d_in[8];
    const float* b_f   = (const float*)d_in[9];
    const float* Wih_b = (const float*)d_in[10];
    const float* Whh_b = (const float*)d_in[11];
    const float* b_b   = (const float*)d_in[12];
    const float* ffn_w = (const float*)d_in[13];
    const float* ffn_b = (const float*)d_in[14];
    float* out = (float*)d_out;

    float* ws = (float*)d_ws;
    float* WihT_f = ws;                      // 160000 floats each
    float* WihT_b = WihT_f + 160000;
    float* x   = WihT_b + 160000;            // 3,276,800
    float* xgf = x + 3276800;                // 13,107,200
    float* xgb = xgf + 13107200;             // 13,107,200
    float* hf  = xgb + 13107200;             // 3,276,800
    float* hb  = hf + 3276800;               // 3,276,800

    // NaN-fill h buffers: the data word itself is the readiness flag.
    (void)hipMemsetAsync(hf, 0xFF, 3276800 * sizeof(float), stream);
    (void)hipMemsetAsync(hb, 0xFF, 3276800 * sizeof(float), stream);
    transpose_k<<<625, 256, 0, stream>>>(Wih_f, WihT_f);
    transpose_k<<<625, 256, 0, stream>>>(Wih_b, WihT_b);
    embed_k<<<(B * S * IN2 + 255) / 256, 256, 0, stream>>>(chars, bichars, cw, bw, x);
    xg_k<<<dim3(B * S / 16, 2), 256, 0, stream>>>(x, WihT_f, b_f, WihT_b, b_b, xgf, xgb);
    lstm_k<<<256, 1024, 0, stream>>>(xgf, xgb, Whh_f, Whh_b, hf, hb);
    out_k<<<(B * SK * W) / 4, 256, 0, stream>>>(subwords, prew, subw, hf, hb, ffn_w, ffn_b, out);
}